// Round 1
// baseline (337.838 us; speedup 1.0000x reference)
//
#include <hip/hip_runtime.h>
#include <hip/hip_bf16.h>

#define NN 50000
#define NE 1600000
#define FF 128
#define CC 16
#define NB ((NN + 63) / 64)       // 782 dst-buckets of 64 nodes
#define NBLK 256                  // partition blocks for the sort (all CUs)
#define CH ((NE + NBLK - 1) / NBLK)   // 6250 edges per partition block

using bf16 = __hip_bfloat16;
using bf16x8 = __attribute__((ext_vector_type(8))) short;   // 8 bf16 = 4 VGPRs
using f32x4  = __attribute__((ext_vector_type(4))) float;

// Runtime-dtype load: isbf selects bf16 vs f32 interpretation of p.
static __device__ __forceinline__ float ldf(const void* p, int i, int isbf){
    return isbf ? __bfloat162float(((const bf16*)p)[i]) : ((const float*)p)[i];
}
static __device__ __forceinline__ float bflo(unsigned u){
    union{unsigned x; float f;} c; c.x = u << 16; return c.f;
}
static __device__ __forceinline__ float bfhi(unsigned u){
    union{unsigned x; float f;} c; c.x = u & 0xFFFF0000u; return c.f;
}
static __device__ __forceinline__ float rdlanef(float v, int l){
    return __int_as_float(__builtin_amdgcn_readlane(__float_as_int(v), l));
}
static __device__ __forceinline__ unsigned short f2bfu(float v){
    bf16 b = __float2bfloat16(v);
    union{bf16 b; unsigned short u;} c; c.b = b; return c.u;
}

// ---------------- fused prep: dtype detect + bcounts zero + W1/W2/W3 transpose->bf16 ----------------
__global__ __launch_bounds__(256) void k_prep(const unsigned short* __restrict__ featu,
                                              const void* __restrict__ W1, const void* __restrict__ W2,
                                              const void* __restrict__ W3, int* __restrict__ dflag,
                                              int* __restrict__ bcounts, unsigned short* __restrict__ wtg){
    __shared__ int cnt;
    const int t = threadIdx.x;
    if (t == 0) cnt = 0;
    __syncthreads();
    unsigned short lo = featu[2 * t];
    int e = (lo >> 7) & 0xFF;
    if (e >= 117 && e <= 137) atomicAdd(&cnt, 1);
    __syncthreads();
    const int isbf = (cnt >= 128) ? 1 : 0;   // 1 => bf16 inputs
    int idx = blockIdx.x * 256 + t;
    if (idx == 0) *dflag = isbf;
    if (idx < NB) bcounts[idx] = 0;
    if (idx < 32768){
        int l = idx >> 14;                   // 0: W1, 1: W2
        int e2 = idx & 16383;
        int f = e2 >> 7, k = e2 & 127;
        const void* W = l ? W2 : W1;
        wtg[idx] = f2bfu(ldf(W, k * FF + f, isbf));
    } else if (idx < 34816){
        int e2 = idx - 32768;                // W3t: 16x128
        int f = e2 >> 7, k = e2 & 127;
        wtg[idx] = f2bfu(ldf(W3, k * CC + f, isbf));
    }
}

// ---------------- CSR build: hierarchical counting sort by dst ----------------

__global__ __launch_bounds__(256) void k_bcount(const int* __restrict__ dst, int* __restrict__ bcounts,
                                                int* __restrict__ bh){
    __shared__ int hist[NB];
    const int t = threadIdx.x, b = blockIdx.x;
    for (int i = t; i < NB; i += 256) hist[i] = 0;
    __syncthreads();
    const int beg = b * CH, end = (beg + CH < NE) ? beg + CH : NE;
    for (int i = beg + t; i < end; i += 256){
        int d = dst[i];
        if ((unsigned)d >= NN) d = 0;
        atomicAdd(&hist[d >> 6], 1);
    }
    __syncthreads();
    for (int k = t; k < NB; k += 256){
        int v = hist[k];
        bh[k * NBLK + b] = v;
        if (v) atomicAdd(&bcounts[k], v);
    }
}

__global__ __launch_bounds__(256) void k_bscan(const int* __restrict__ bcounts, int* __restrict__ bbase,
                                               int* __restrict__ rowptr){
    __shared__ int s[256];
    const int t = threadIdx.x;
    constexpr int PT = (NB + 255) / 256;   // 4
    int loc[PT];
    int sum = 0;
    #pragma unroll
    for (int i = 0; i < PT; i++){
        int idx = t * PT + i;
        int v = (idx < NB) ? bcounts[idx] : 0;
        loc[i] = sum;
        sum += v;
    }
    s[t] = sum; __syncthreads();
    for (int off = 1; off < 256; off <<= 1){
        int x = (t >= off) ? s[t - off] : 0;
        __syncthreads();
        s[t] += x;
        __syncthreads();
    }
    int base = (t > 0) ? s[t - 1] : 0;
    #pragma unroll
    for (int i = 0; i < PT; i++){
        int idx = t * PT + i;
        if (idx < NB) bbase[idx] = base + loc[i];
    }
    if (t == 255){
        bbase[NB] = s[255];      // == NE
        rowptr[NN] = s[255];
    }
}

// Per-bucket offsets: wave-per-bucket shfl scan over the 256 per-block counts (4/lane).
__global__ __launch_bounds__(256) void k_boffset(const int* __restrict__ bbase, int* __restrict__ bh){
    int k = blockIdx.x * 4 + (threadIdx.x >> 6);
    int lane = threadIdx.x & 63;
    if (k >= NB) return;
    int v[4];
    int s = 0;
    #pragma unroll
    for (int i = 0; i < 4; i++){
        v[i] = bh[k * NBLK + 4 * lane + i];
        s += v[i];
    }
    int tot = s;
    #pragma unroll
    for (int off = 1; off < 64; off <<= 1){
        int x = __shfl_up(s, off);
        if (lane >= off) s += x;
    }
    int run = bbase[k] + s - tot;   // exclusive prefix of per-lane sums
    #pragma unroll
    for (int i = 0; i < 4; i++){
        bh[k * NBLK + 4 * lane + i] = run;
        run += v[i];
    }
}

__global__ __launch_bounds__(256) void k_bucket(const int* __restrict__ src, const int* __restrict__ dst,
                                                const int* __restrict__ bh, unsigned* __restrict__ bpairs){
    __shared__ int cur[NB];
    const int t = threadIdx.x, b = blockIdx.x;
    for (int k = t; k < NB; k += 256) cur[k] = bh[k * NBLK + b];
    __syncthreads();
    const int beg = b * CH, end = (beg + CH < NE) ? beg + CH : NE;
    for (int i = beg + t; i < end; i += 256){
        int s = src[i];
        int d = dst[i];
        if ((unsigned)s >= NN) s = 0;
        if ((unsigned)d >= NN) d = 0;
        int p = atomicAdd(&cur[d >> 6], 1);
        if ((unsigned)p < NE) bpairs[p] = (unsigned)s | ((unsigned)(d & 63) << 16);
    }
}

__global__ __launch_bounds__(256) void k_bsort(const unsigned* __restrict__ bpairs, const int* __restrict__ bbase,
                                               int* __restrict__ rowptr, int* __restrict__ csrsrc){
    __shared__ int cnt[64];
    __shared__ int cur[64];
    const int t = threadIdx.x;
    const int b = blockIdx.x;
    const int base = bbase[b];
    const int endb = bbase[b + 1];
    if (t < 64) cnt[t] = 0;
    __syncthreads();
    for (int i = base + t; i < endb; i += 256)
        atomicAdd(&cnt[bpairs[i] >> 16], 1);
    __syncthreads();
    if (t < 64){   // wave 0 exactly: 64-lane exclusive scan via shfl
        int v = cnt[t];
        int inc = v;
        #pragma unroll
        for (int off = 1; off < 64; off <<= 1){
            int x = __shfl_up(inc, off);
            if (t >= off) inc += x;
        }
        int excl = inc - v;
        cur[t] = excl;
        int d = b * 64 + t;
        if (d < NN) rowptr[d] = base + excl;
    }
    __syncthreads();
    for (int i = base + t; i < endb; i += 256){
        unsigned pr = bpairs[i];
        int p = atomicAdd(&cur[pr >> 16], 1);
        csrsrc[base + p] = (int)(pr & 0xFFFFu);
    }
}

// ---------------- MFMA GEMM (layers 1-2), LDS-FREE: fragments loaded straight from global ----------------
// A-frag: 16B of row X[row], offset quad*16 + kt*64 bytes (bf16-packed) — 64 lanes
// cover 16 full cache lines. B-frag: 16B from the 32KB wtg (L1-resident after 1st wave).
// Out-of-range rows clamp to row 0: A-row m only feeds output-row m, discarded by guard.

template<bool XDYN>
__global__ __launch_bounds__(256) void k_mgemm(const void* __restrict__ X, const unsigned short* __restrict__ wtg,
                                               const void* __restrict__ al, const void* __restrict__ ar,
                                               const int* __restrict__ dflag, bf16* __restrict__ ft,
                                               float* __restrict__ el, float* __restrict__ er){
    const int isbf = *dflag;
    const int t  = threadIdx.x;
    const int n0 = blockIdx.x * 64;
    const int wv = t >> 6;
    const int lane = t & 63;
    const int quad = lane >> 4;
    const int mcol = lane & 15;
    const int row = n0 + wv * 16 + mcol;
    const int rc  = (row < NN) ? row : 0;   // clamped A row

    bf16x8 afr[4];
    if (XDYN && !isbf){
        // f32 input: load 8 floats per fragment, convert+pack in-register.
        const float* xr = (const float*)X + rc * FF + quad * 8;
        #pragma unroll
        for (int kt = 0; kt < 4; kt++){
            float4 a = *(const float4*)(xr + kt * 32);
            float4 b = *(const float4*)(xr + kt * 32 + 4);
            union { bf16x8 v; unsigned u[4]; } c;
            c.u[0] = (unsigned)f2bfu(a.x) | ((unsigned)f2bfu(a.y) << 16);
            c.u[1] = (unsigned)f2bfu(a.z) | ((unsigned)f2bfu(a.w) << 16);
            c.u[2] = (unsigned)f2bfu(b.x) | ((unsigned)f2bfu(b.y) << 16);
            c.u[3] = (unsigned)f2bfu(b.z) | ((unsigned)f2bfu(b.w) << 16);
            afr[kt] = c.v;
        }
    } else {
        // bf16-packed rows (bf16 input or bf16 workspace hB).
        const unsigned short* xr = (const unsigned short*)X + rc * FF + quad * 8;
        #pragma unroll
        for (int kt = 0; kt < 4; kt++)
            afr[kt] = *(const bf16x8*)(xr + kt * 32);
    }

    float elp[4] = {0.f,0.f,0.f,0.f}, erp[4] = {0.f,0.f,0.f,0.f};

    #pragma unroll
    for (int f = 0; f < 8; f++){
        f32x4 acc = {0.f, 0.f, 0.f, 0.f};
        const unsigned short* wr = wtg + (f * 16 + mcol) * FF + quad * 8;
        #pragma unroll
        for (int kt = 0; kt < 4; kt++){
            bf16x8 bfr = *(const bf16x8*)(wr + kt * 32);
            acc = __builtin_amdgcn_mfma_f32_16x16x32_bf16(afr[kt], bfr, acc, 0, 0, 0);
        }
        int col = f * 16 + mcol;
        float alv = ldf(al, col, isbf);
        float arv = ldf(ar, col, isbf);
        #pragma unroll
        for (int reg = 0; reg < 4; reg++){
            int node = n0 + wv * 16 + quad * 4 + reg;
            float v = acc[reg];
            if (node < NN) ft[node * FF + col] = __float2bfloat16(v);
            elp[reg] += v * alv;
            erp[reg] += v * arv;
        }
    }

    #pragma unroll
    for (int reg = 0; reg < 4; reg++){
        float pl = elp[reg], pr = erp[reg];
        #pragma unroll
        for (int off = 1; off < 16; off <<= 1){
            pl += __shfl_xor(pl, off);
            pr += __shfl_xor(pr, off);
        }
        int node = n0 + wv * 16 + quad * 4 + reg;
        if (mcol == 0 && node < NN){ el[node] = pl; er[node] = pr; }
    }
}

// ---------------- MFMA GEMM (layer 3), LDS-FREE: ft3 = X(bf16) @ W3, f32 out ----------------

__global__ __launch_bounds__(256) void k_mgemm3(const void* __restrict__ X, const unsigned short* __restrict__ wt3g,
                                                const void* __restrict__ al, const void* __restrict__ ar,
                                                const int* __restrict__ dflag, float* __restrict__ ft,
                                                float* __restrict__ el, float* __restrict__ er){
    const int isbf = *dflag;
    const int t  = threadIdx.x;
    const int n0 = blockIdx.x * 64;
    const int wv = t >> 6;
    const int lane = t & 63;
    const int quad = lane >> 4;
    const int mcol = lane & 15;
    const int row = n0 + wv * 16 + mcol;
    const int rc  = (row < NN) ? row : 0;

    const unsigned short* xr = (const unsigned short*)X + rc * FF + quad * 8;
    const unsigned short* wr = wt3g + mcol * FF + quad * 8;

    f32x4 acc = {0.f, 0.f, 0.f, 0.f};
    #pragma unroll
    for (int kt = 0; kt < 4; kt++){
        bf16x8 afr = *(const bf16x8*)(xr + kt * 32);
        bf16x8 bfr = *(const bf16x8*)(wr + kt * 32);
        acc = __builtin_amdgcn_mfma_f32_16x16x32_bf16(afr, bfr, acc, 0, 0, 0);
    }

    float alv = ldf(al, mcol, isbf);
    float arv = ldf(ar, mcol, isbf);
    #pragma unroll
    for (int reg = 0; reg < 4; reg++){
        int node = n0 + wv * 16 + quad * 4 + reg;
        float v = acc[reg];
        if (node < NN) ft[node * CC + mcol] = v;
        float pl = v * alv, pr = v * arv;
        #pragma unroll
        for (int off = 1; off < 16; off <<= 1){
            pl += __shfl_xor(pl, off);
            pr += __shfl_xor(pr, off);
        }
        if (mcol == 0 && node < NN){ el[node] = pl; er[node] = pr; }
    }
}

// ---------------- Aggregation (128 feats, bf16 ft): dwordx4 gather, 4 edges/instr ----------------
// Lane layout for the gather loop: g = lane>>4 picks one of 4 edges in the batch,
// c = lane&15 picks a 16B chunk (8 bf16 feats) of the 256B row. One global_load_dwordx4
// moves 4 edges x 16B = 1KB/wave-instr (vs 256B with per-lane dword loads), and the
// per-edge (s,w) broadcast is one ds_bpermute per 4 edges instead of 2 readlanes/edge.
// Partial sums per group are recombined with shfl_xor(16/32); output layout unchanged.

__global__ __launch_bounds__(256) void k_agg128(const void* __restrict__ ftv, const float* __restrict__ el,
                                                const float* __restrict__ er, const int* __restrict__ rowptr,
                                                const int* __restrict__ csrsrc, const void* __restrict__ bias,
                                                const int* __restrict__ dflag, unsigned* __restrict__ outp){
    const int isbf = *dflag;
    int lane = threadIdx.x & 63;
    int n = blockIdx.x * 4 + (threadIdx.x >> 6);
    if (n >= NN) return;
    int beg = rowptr[n], end = rowptr[n + 1];
    beg = (beg < 0) ? 0 : (beg > NE ? NE : beg);
    end = (end < beg) ? beg : (end > NE ? NE : end);
    int deg = end - beg;
    float erd = er[n];

    // First pass: per-lane edge weight (<=64 edges), running max.
    float m = -3.4e38f;
    int   s_c = 0;
    float e_c = 0.f;
    for (int i = beg + lane; i < end; i += 64){
        int s = csrsrc[i];
        if ((unsigned)s >= NN) s = 0;
        float e = el[s] + erd;
        e = (e >= 0.f) ? e : 0.2f * e;
        if (i < beg + 64){ s_c = s; e_c = e; }
        m = fmaxf(m, e);
    }
    #pragma unroll
    for (int off = 32; off; off >>= 1) m = fmaxf(m, __shfl_xor(m, off));

    int jmax = (deg < 64) ? deg : 64;
    float w_c = (lane < jmax) ? __expf(e_c - m) : 0.f;
    float lsum = w_c;
    #pragma unroll
    for (int off = 32; off; off >>= 1) lsum += __shfl_xor(lsum, off);

    // Gather loop: batches of 4 edges, groups of 4 batches (16 edges) for MLP.
    const int g = lane >> 4;     // edge slot in batch
    const int c = lane & 15;     // 16B chunk -> features c*8 .. c*8+7
    const uint4* ftq4 = (const uint4*)ftv;   // row s at ftq4[s*16 + c]
    float acc[8] = {0.f,0.f,0.f,0.f,0.f,0.f,0.f,0.f};
    int jmax4 = (jmax + 3) & ~3;

    for (int base = 0; base < jmax4; base += 16){
        uint4 u[4];
        float wB[4];
        #pragma unroll
        for (int q = 0; q < 4; q++){
            int jj = base + q * 4;
            if (jj < jmax4){
                int idx = jj + g;                         // < 64 always
                int sE = __shfl(s_c, idx);
                wB[q] = __shfl(w_c, idx);                 // 0 for padded slots
                u[q] = ftq4[(unsigned)sE * 16u + c];
            } else {
                wB[q] = 0.f;
                u[q] = (uint4){0u, 0u, 0u, 0u};
            }
        }
        #pragma unroll
        for (int q = 0; q < 4; q++){
            float w = wB[q];
            acc[0] += w * bflo(u[q].x); acc[1] += w * bfhi(u[q].x);
            acc[2] += w * bflo(u[q].y); acc[3] += w * bfhi(u[q].y);
            acc[4] += w * bflo(u[q].z); acc[5] += w * bfhi(u[q].z);
            acc[6] += w * bflo(u[q].w); acc[7] += w * bfhi(u[q].w);
        }
    }

    // Tail (deg > 64): essentially never taken for this graph (Poisson mean 32).
    for (int i = beg + 64; i < end; ++i){
        int s = csrsrc[i];
        if ((unsigned)s >= NN) s = 0;
        float e = el[s] + erd;
        e = (e >= 0.f) ? e : 0.2f * e;
        float w = __expf(e - m);
        lsum += w;
        if (g == 0){
            uint4 u = ftq4[(unsigned)s * 16u + c];
            acc[0] += w * bflo(u.x); acc[1] += w * bfhi(u.x);
            acc[2] += w * bflo(u.y); acc[3] += w * bfhi(u.y);
            acc[4] += w * bflo(u.z); acc[5] += w * bfhi(u.z);
            acc[6] += w * bflo(u.w); acc[7] += w * bfhi(u.w);
        }
    }

    // Combine the 4 per-group partials: lanes sharing c sum across g.
    #pragma unroll
    for (int k = 0; k < 8; k++){
        acc[k] += __shfl_xor(acc[k], 16);
        acc[k] += __shfl_xor(acc[k], 32);
    }

    if (g == 0){
        float inv = 1.f / ((lsum > 0.f) ? lsum : 1.f);
        float o[8];
        #pragma unroll
        for (int k = 0; k < 8; k++)
            o[k] = fmaxf(acc[k] * inv + ldf(bias, c * 8 + k, isbf), 0.f);
        uint4 pk;
        pk.x = (unsigned)f2bfu(o[0]) | ((unsigned)f2bfu(o[1]) << 16);
        pk.y = (unsigned)f2bfu(o[2]) | ((unsigned)f2bfu(o[3]) << 16);
        pk.z = (unsigned)f2bfu(o[4]) | ((unsigned)f2bfu(o[5]) << 16);
        pk.w = (unsigned)f2bfu(o[6]) | ((unsigned)f2bfu(o[7]) << 16);
        ((uint4*)outp)[n * 16 + c] = pk;
    }
}

// ---------------- Aggregation (16 feats, f32 ft): 4-lane edge groups, final output ----------------

__global__ __launch_bounds__(256) void k_agg16(const float* __restrict__ ftv, const float* __restrict__ el,
                                               const float* __restrict__ er, const int* __restrict__ rowptr,
                                               const int* __restrict__ csrsrc, const void* __restrict__ bias,
                                               const int* __restrict__ dflag, void* __restrict__ outp){
    const int isbf = *dflag;
    int lane = threadIdx.x & 63;
    int n = blockIdx.x * 4 + (threadIdx.x >> 6);
    if (n >= NN) return;
    int beg = rowptr[n], end = rowptr[n + 1];
    beg = (beg < 0) ? 0 : (beg > NE ? NE : beg);
    end = (end < beg) ? beg : (end > NE ? NE : end);
    int deg = end - beg;
    float erd = er[n];

    float m = -3.4e38f;
    int   s_c = 0;
    float e_c = 0.f;
    for (int i = beg + lane; i < end; i += 64){
        int s = csrsrc[i];
        if ((unsigned)s >= NN) s = 0;
        float e = el[s] + erd;
        e = (e >= 0.f) ? e : 0.2f * e;
        if (i < beg + 64){ s_c = s; e_c = e; }
        m = fmaxf(m, e);
    }
    #pragma unroll
    for (int off = 32; off; off >>= 1) m = fmaxf(m, __shfl_xor(m, off));

    int jmax = (deg < 64) ? deg : 64;
    float w_c = (lane < jmax) ? __expf(e_c - m) : 0.f;
    float lsum = w_c;
    #pragma unroll
    for (int off = 32; off; off >>= 1) lsum += __shfl_xor(lsum, off);

    const float4* ftq = (const float4*)ftv;   // row n at ftq[n*4 + fl2]
    const int g   = lane >> 2;    // edge-in-batch 0..15
    const int fl2 = lane & 3;
    int nbatch = (jmax + 15) >> 4;    // <= 4
    float wq[4]; float4 uq[4];
    #pragma unroll
    for (int q = 0; q < 4; q++){
        int eidx = (q * 16 + g) & 63;
        int s = __shfl(s_c, eidx);
        wq[q] = (q < nbatch) ? __shfl(w_c, eidx) : 0.f;
        uq[q] = ftq[(unsigned)s * 4 + fl2];
    }
    float a4[4] = {0.f,0.f,0.f,0.f};
    #pragma unroll
    for (int q = 0; q < 4; q++){
        a4[0] += wq[q] * uq[q].x;
        a4[1] += wq[q] * uq[q].y;
        a4[2] += wq[q] * uq[q].z;
        a4[3] += wq[q] * uq[q].w;
    }
    for (int i = beg + 64; i < end; ++i){
        int s = csrsrc[i];
        if ((unsigned)s >= NN) s = 0;
        float e = el[s] + erd;
        e = (e >= 0.f) ? e : 0.2f * e;
        float w = __expf(e - m);
        lsum += w;
        if (g == 0){
            float4 u = ftq[(unsigned)s * 4 + fl2];
            a4[0] += w * u.x; a4[1] += w * u.y; a4[2] += w * u.z; a4[3] += w * u.w;
        }
    }
    #pragma unroll
    for (int i = 0; i < 4; i++){
        a4[i] += __shfl_xor(a4[i], 4);
        a4[i] += __shfl_xor(a4[i], 8);
        a4[i] += __shfl_xor(a4[i], 16);
        a4[i] += __shfl_xor(a4[i], 32);
    }
    float inv = 1.f / ((lsum > 0.f) ? lsum : 1.f);
    if (lane < 4){
        float o0 = fmaxf(a4[0] * inv + ldf(bias, fl2 * 4 + 0, isbf), 0.f);
        float o1 = fmaxf(a4[1] * inv + ldf(bias, fl2 * 4 + 1, isbf), 0.f);
        float o2 = fmaxf(a4[2] * inv + ldf(bias, fl2 * 4 + 2, isbf), 0.f);
        float o3 = fmaxf(a4[3] * inv + ldf(bias, fl2 * 4 + 3, isbf), 0.f);
        if (isbf){
            uint2 pk;
            pk.x = (unsigned)f2bfu(o0) | ((unsigned)f2bfu(o1) << 16);
            pk.y = (unsigned)f2bfu(o2) | ((unsigned)f2bfu(o3) << 16);
            ((uint2*)outp)[n * 4 + fl2] = pk;
        } else {
            float4 o; o.x = o0; o.y = o1; o.z = o2; o.w = o3;
            ((float4*)outp)[n * 4 + fl2] = o;
        }
    }
}

// ---------------- host launch ----------------

static size_t align256(size_t x){ return (x + 255) & ~(size_t)255; }

extern "C" void kernel_launch(void* const* d_in, const int* in_sizes, int n_in,
                              void* d_out, int out_size, void* d_ws, size_t ws_size,
                              hipStream_t stream) {
    const void* feat = d_in[0];
    const int*  src  = (const int*)d_in[1];
    const int*  dst  = (const int*)d_in[2];
    const void* W1 = d_in[3];
    const void* al1= d_in[4];
    const void* ar1= d_in[5];
    const void* b1 = d_in[6];
    const void* W2 = d_in[7];
    const void* al2= d_in[8];
    const void* ar2= d_in[9];
    const void* b2 = d_in[10];
    const void* W3 = d_in[11];
    const void* al3= d_in[12];
    const void* ar3= d_in[13];
    const void* b3 = d_in[14];

    // workspace carve
    char* p = (char*)d_ws;
    size_t off = 0;
    auto carve = [&](size_t bytes)->void*{
        void* r = p + off;
        off += align256(bytes);
        return r;
    };
    float* ftA   = (float*)carve((size_t)NN * FF * 4);   // ft buffer: bf16 view (layers 1/2), f32 view (layer 3)
    unsigned* hB = (unsigned*)carve((size_t)NN * FF * 4); // hidden state bf16-packed; bpairs overlays pre-layer-1
    float* el    = (float*)carve((size_t)NN * 4);
    float* er    = (float*)carve((size_t)NN * 4);
    int*   rowptr= (int*)  carve((size_t)(NN + 1) * 4);
    int*   csrsrc= (int*)  carve((size_t)NE * 4);
    int*   bcounts=(int*)  carve((size_t)NB * 4);
    int*   bbase  =(int*)  carve((size_t)(NB + 1) * 4);
    int*   bh     =(int*)  carve((size_t)NB * NBLK * 4);  // per-(bucket,block) hist/offsets, 800KB
    unsigned short* wtg = (unsigned short*)carve((size_t)34816 * 2);  // W1t,W2t,W3t bf16
    int*   dflag  =(int*)  carve(256);
    unsigned* bpairs = (unsigned*)hB;   // overlay: consumed before hB is first written
    void*  ftb   = ftA;                 // bf16 ft view (layers 1-2); f32 ft3 view (layer 3)
    (void)ws_size; (void)n_in; (void)in_sizes; (void)out_size;

    dim3 b256(256);

    // fused prep: dtype detect + bcounts zero + weight transpose
    k_prep<<<dim3(136), b256, 0, stream>>>((const unsigned short*)feat, W1, W2, W3, dflag, bcounts, wtg);

    // CSR build via hierarchical counting sort
    k_bcount<<<dim3(NBLK), b256, 0, stream>>>(dst, bcounts, bh);
    k_bscan<<<dim3(1), b256, 0, stream>>>(bcounts, bbase, rowptr);
    k_boffset<<<dim3((NB + 3) / 4), b256, 0, stream>>>(bbase, bh);
    k_bucket<<<dim3(NBLK), b256, 0, stream>>>(src, dst, bh, bpairs);
    k_bsort<<<dim3(NB), b256, 0, stream>>>(bpairs, bbase, rowptr, csrsrc);

    const int mg_grid   = (NN + 63) / 64;     // 782
    const int node_grid = (NN + 3) / 4;       // 12500

    // Layer 1: feat @ W1 -> ftb(bf16) + el/er; agg -> hB (bf16-packed)
    k_mgemm<true><<<dim3(mg_grid), b256, 0, stream>>>(feat, wtg, al1, ar1, dflag, (bf16*)ftb, el, er);
    k_agg128<<<dim3(node_grid), b256, 0, stream>>>(ftb, el, er, rowptr, csrsrc, b1, dflag, hB);

    // Layer 2: hB(bf16) @ W2 -> ftb(bf16) + el/er; agg -> hB
    k_mgemm<false><<<dim3(mg_grid), b256, 0, stream>>>(hB, wtg + 16384, al2, ar2, dflag, (bf16*)ftb, el, er);
    k_agg128<<<dim3(node_grid), b256, 0, stream>>>(ftb, el, er, rowptr, csrsrc, b2, dflag, hB);

    // Layer 3: hB(bf16) @ W3 -> ft3(f32) + el/er; agg -> d_out
    k_mgemm3<<<dim3(mg_grid), b256, 0, stream>>>(hB, wtg + 32768, al3, ar3, dflag, (float*)ftb, el, er);
    k_agg16<<<dim3(node_grid), b256, 0, stream>>>((const float*)ftb, el, er, rowptr, csrsrc, b3, dflag, d_out);
}